// Round 1
// baseline (17555.429 us; speedup 1.0000x reference)
//
#include <hip/hip_runtime.h>
#include <math.h>

#define NB 16
#define NT 512
#define NE 1024
#define ND 1024
#define NA 1024
#define NO 10000
#define NL 128
#define NOL 129
#define NROWS (NB*NOL)   /* 2064 */
#define TOK_SOS 9999
#define TOK_EOS 9999

__device__ __forceinline__ float sigf(float x){ return 1.0f/(1.0f+expf(-x)); }

// ---------------- zero ----------------
__global__ void zero_kernel(float* __restrict__ p, int n){
  int i = blockIdx.x*256 + threadIdx.x;
  if (i < n) p[i] = 0.0f;
}

// ---------------- pre_enc = tanh(mask(hpad) @ Wenc), [8192,1024] ----------------
__global__ __launch_bounds__(256) void preenc_kernel(
    const float* __restrict__ hpad, const int* __restrict__ hlen,
    const float* __restrict__ Wenc, float* __restrict__ pre){
  __shared__ float As[32][68];
  __shared__ float Bs[32][68];
  const int m0 = blockIdx.x*64, n0 = blockIdx.y*64;
  const int tid = threadIdx.x;
  const int ty = tid>>4, tx = tid&15;
  const int ar = tid>>2, akg = (tid&3)*8;
  const int am = m0 + ar;
  const bool arow_on = ((am & 511) < hlen[am >> 9]);
  const int bk = tid>>3, bng = (tid&7)*8;
  float acc[4][4] = {{0.0f}};
  for (int k0=0; k0<NE; k0+=32){
    float4 a0 = make_float4(0,0,0,0), a1 = make_float4(0,0,0,0);
    if (arow_on){
      const float4* s = (const float4*)(hpad + (size_t)am*NE + k0 + akg);
      a0 = s[0]; a1 = s[1];
    }
    As[akg+0][ar]=a0.x; As[akg+1][ar]=a0.y; As[akg+2][ar]=a0.z; As[akg+3][ar]=a0.w;
    As[akg+4][ar]=a1.x; As[akg+5][ar]=a1.y; As[akg+6][ar]=a1.z; As[akg+7][ar]=a1.w;
    {
      const float4* s = (const float4*)(Wenc + (size_t)(k0+bk)*NA + n0 + bng);
      *(float4*)&Bs[bk][bng]   = s[0];
      *(float4*)&Bs[bk][bng+4] = s[1];
    }
    __syncthreads();
    #pragma unroll
    for (int kk=0; kk<32; ++kk){
      float4 a = *(const float4*)&As[kk][ty*4];
      float4 b = *(const float4*)&Bs[kk][tx*4];
      float av[4]={a.x,a.y,a.z,a.w}, bv[4]={b.x,b.y,b.z,b.w};
      #pragma unroll
      for (int i=0;i<4;++i)
        #pragma unroll
        for (int j=0;j<4;++j) acc[i][j] += av[i]*bv[j];
    }
    __syncthreads();
  }
  #pragma unroll
  for (int i=0;i<4;++i){
    float4 o = make_float4(tanhf(acc[i][0]),tanhf(acc[i][1]),tanhf(acc[i][2]),tanhf(acc[i][3]));
    *(float4*)(pre + (size_t)(m0+ty*4+i)*NA + n0 + tx*4) = o;
  }
}

// ---------------- g_ey = embed[ys_in] @ Wih0[:, 0:1024]^T + bih0 + bhh0, [2064,4096] ----------------
__global__ __launch_bounds__(256) void gey_kernel(
    const int* __restrict__ ys, const float* __restrict__ embed,
    const float* __restrict__ Wih0, const float* __restrict__ bih0,
    const float* __restrict__ bhh0, float* __restrict__ gey){
  __shared__ float As[32][68];
  __shared__ float Bs[32][68];
  const int m0 = blockIdx.x*64, n0 = blockIdx.y*64;
  const int tid = threadIdx.x;
  const int ty = tid>>4, tx = tid&15;
  const int ar = tid>>2, akg = (tid&3)*8;
  const int am = m0 + ar;
  const bool arow_on = (am < NROWS);
  int tok = 0;
  if (arow_on){
    int b = am / NOL, l = am - b*NOL;
    tok = (l==0) ? TOK_SOS : ys[b*NL + l - 1];
  }
  const int bj = tid>>2, bkg = (tid&3)*8;
  float acc[4][4] = {{0.0f}};
  for (int k0=0; k0<ND; k0+=32){
    float4 a0 = make_float4(0,0,0,0), a1 = make_float4(0,0,0,0);
    if (arow_on){
      const float4* s = (const float4*)(embed + (size_t)tok*ND + k0 + akg);
      a0 = s[0]; a1 = s[1];
    }
    As[akg+0][ar]=a0.x; As[akg+1][ar]=a0.y; As[akg+2][ar]=a0.z; As[akg+3][ar]=a0.w;
    As[akg+4][ar]=a1.x; As[akg+5][ar]=a1.y; As[akg+6][ar]=a1.z; As[akg+7][ar]=a1.w;
    {
      const float4* s = (const float4*)(Wih0 + (size_t)(n0+bj)*2048 + k0 + bkg);
      float4 b0 = s[0], b1 = s[1];
      Bs[bkg+0][bj]=b0.x; Bs[bkg+1][bj]=b0.y; Bs[bkg+2][bj]=b0.z; Bs[bkg+3][bj]=b0.w;
      Bs[bkg+4][bj]=b1.x; Bs[bkg+5][bj]=b1.y; Bs[bkg+6][bj]=b1.z; Bs[bkg+7][bj]=b1.w;
    }
    __syncthreads();
    #pragma unroll
    for (int kk=0; kk<32; ++kk){
      float4 a = *(const float4*)&As[kk][ty*4];
      float4 b = *(const float4*)&Bs[kk][tx*4];
      float av[4]={a.x,a.y,a.z,a.w}, bv[4]={b.x,b.y,b.z,b.w};
      #pragma unroll
      for (int i=0;i<4;++i)
        #pragma unroll
        for (int j=0;j<4;++j) acc[i][j] += av[i]*bv[j];
    }
    __syncthreads();
  }
  #pragma unroll
  for (int i=0;i<4;++i){
    int row = m0+ty*4+i;
    if (row < NROWS){
      int col = n0 + tx*4;
      float4 o = make_float4(acc[i][0]+bih0[col+0]+bhh0[col+0],
                             acc[i][1]+bih0[col+1]+bhh0[col+1],
                             acc[i][2]+bih0[col+2]+bhh0[col+2],
                             acc[i][3]+bih0[col+3]+bhh0[col+3]);
      *(float4*)(gey + (size_t)row*4096 + col) = o;
    }
  }
}

// ---------------- logits = z_all @ Wout + bout, [2064,10000] ----------------
__global__ __launch_bounds__(256) void logits_kernel(
    const float* __restrict__ zall, const float* __restrict__ Wout,
    const float* __restrict__ bout, float* __restrict__ logits){
  __shared__ float As[32][68];
  __shared__ float Bs[32][68];
  const int m0 = blockIdx.x*64, n0 = blockIdx.y*64;
  const int tid = threadIdx.x;
  const int ty = tid>>4, tx = tid&15;
  const int ar = tid>>2, akg = (tid&3)*8;
  const int am = m0 + ar;
  const bool arow_on = (am < NROWS);
  const int bk = tid>>3, bng = (tid&7)*8;
  const bool nfull = (n0 + 64 <= NO);
  float acc[4][4] = {{0.0f}};
  for (int k0=0; k0<ND; k0+=32){
    float4 a0 = make_float4(0,0,0,0), a1 = make_float4(0,0,0,0);
    if (arow_on){
      const float4* s = (const float4*)(zall + (size_t)am*ND + k0 + akg);
      a0 = s[0]; a1 = s[1];
    }
    As[akg+0][ar]=a0.x; As[akg+1][ar]=a0.y; As[akg+2][ar]=a0.z; As[akg+3][ar]=a0.w;
    As[akg+4][ar]=a1.x; As[akg+5][ar]=a1.y; As[akg+6][ar]=a1.z; As[akg+7][ar]=a1.w;
    if (nfull){
      const float4* s = (const float4*)(Wout + (size_t)(k0+bk)*NO + n0 + bng);
      *(float4*)&Bs[bk][bng]   = s[0];
      *(float4*)&Bs[bk][bng+4] = s[1];
    } else {
      #pragma unroll
      for (int i=0;i<8;++i){
        int n = n0 + bng + i;
        Bs[bk][bng+i] = (n < NO) ? Wout[(size_t)(k0+bk)*NO + n] : 0.0f;
      }
    }
    __syncthreads();
    #pragma unroll
    for (int kk=0; kk<32; ++kk){
      float4 a = *(const float4*)&As[kk][ty*4];
      float4 b = *(const float4*)&Bs[kk][tx*4];
      float av[4]={a.x,a.y,a.z,a.w}, bv[4]={b.x,b.y,b.z,b.w};
      #pragma unroll
      for (int i=0;i<4;++i)
        #pragma unroll
        for (int j=0;j<4;++j) acc[i][j] += av[i]*bv[j];
    }
    __syncthreads();
  }
  #pragma unroll
  for (int i=0;i<4;++i){
    int row = m0+ty*4+i;
    if (row < NROWS){
      #pragma unroll
      for (int j=0;j<4;++j){
        int col = n0 + tx*4 + j;
        if (col < NO) logits[(size_t)row*NO + col] = acc[i][j] + bout[col];
      }
    }
  }
}

// ---------------- dq = tanh(z0 @ Wdec), [16,1024] ----------------
__device__ __forceinline__ void dq_body(int bx, int tid,
    const float* __restrict__ z0, const float* __restrict__ Wdec, float* __restrict__ dq){
  int a = (bx&3)*256 + tid;
  int b = bx>>2;
  const float* z = z0 + b*ND;
  float acc = 0.0f;
  #pragma unroll 8
  for (int d=0; d<ND; ++d) acc += z[d]*Wdec[(size_t)d*NA + a];
  dq[b*NA + a] = tanhf(acc);
}
__global__ __launch_bounds__(256) void dq_kernel(
    const float* __restrict__ z0, const float* __restrict__ Wdec, float* __restrict__ dq){
  dq_body(blockIdx.x, threadIdx.x, z0, Wdec, dq);
}

// ---------------- escore = 2 * (pre_enc . dq), [16,512] ----------------
__device__ __forceinline__ void escore_body(int bx, int tid,
    const float* __restrict__ pre, const float* __restrict__ dq, float* __restrict__ esc){
  int row = bx*4 + (tid>>6);
  int lane = tid&63;
  int b = row>>9;
  const float* pe = pre + (size_t)row*NA;
  const float* q = dq + b*NA;
  float acc = 0.0f;
  #pragma unroll
  for (int a=lane; a<NA; a+=64) acc += pe[a]*q[a];
  #pragma unroll
  for (int off=32; off>0; off>>=1) acc += __shfl_down(acc, off, 64);
  if (lane==0) esc[row] = 2.0f*acc;
}
__global__ __launch_bounds__(256) void escore_kernel(
    const float* __restrict__ pre, const float* __restrict__ dq, float* __restrict__ esc){
  escore_body(blockIdx.x, threadIdx.x, pre, dq, esc);
}

// ---------------- softmax + att_c, [16,1024] ----------------
__global__ __launch_bounds__(256) void attc_kernel(
    const float* __restrict__ esc, const int* __restrict__ hlen,
    const float* __restrict__ hpad, float* __restrict__ attc){
  __shared__ float w[NT];
  __shared__ float red[256];
  const int b = blockIdx.y;
  const int e0 = blockIdx.x*256;
  const int tid = threadIdx.x;
  const int len = hlen[b];
  float s0 = (tid < len)     ? esc[b*NT + tid]       : -INFINITY;
  float s1 = (tid+256 < len) ? esc[b*NT + tid + 256] : -INFINITY;
  red[tid] = fmaxf(s0, s1);
  __syncthreads();
  for (int s=128; s>0; s>>=1){ if (tid<s) red[tid] = fmaxf(red[tid], red[tid+s]); __syncthreads(); }
  float mx = red[0];
  __syncthreads();
  float p0 = (tid < len)     ? expf(s0-mx) : 0.0f;
  float p1 = (tid+256 < len) ? expf(s1-mx) : 0.0f;
  red[tid] = p0+p1;
  __syncthreads();
  for (int s=128; s>0; s>>=1){ if (tid<s) red[tid] += red[tid+s]; __syncthreads(); }
  float inv = 1.0f/red[0];
  w[tid] = p0*inv; w[tid+256] = p1*inv;
  __syncthreads();
  const int e = e0 + tid;
  const float* hp = hpad + (size_t)b*NT*NE + e;
  float acc = 0.0f;
  #pragma unroll 4
  for (int t=0; t<NT; ++t) acc += w[t]*hp[(size_t)t*NE];
  attc[b*NE + e] = acc;
}

// ---------------- step GEMM: out[16,4096] partial (K-split 4) ----------------
__device__ __forceinline__ void stepgemm_body(int ntile, int ks, int tid,
    const float* __restrict__ A1, const float* __restrict__ A2,
    const float* __restrict__ B1, int ldb1, int offb1,
    const float* __restrict__ B2, float* __restrict__ outp,
    float (&As)[32][17], float (&Bs)[32][68]){
  const int n0 = ntile*64;
  const int ty = tid>>4, tx = tid&15;
  const int am1 = tid>>5, ak = tid&31;
  const int am2 = am1+8;
  const int bj = tid>>2, bkg = (tid&3)*8;
  const int kbase = ks*512;
  float acc[4] = {0,0,0,0};
  for (int k0=0; k0<512; k0+=32){
    const int kg = kbase + k0;
    const float* Asrc; int koff;
    const float* Bsrc; int bstr, boff;
    if (kg < 1024){ Asrc = A1; koff = kg;      Bsrc = B1; bstr = ldb1; boff = offb1 + kg; }
    else          { Asrc = A2; koff = kg-1024; Bsrc = B2; bstr = 1024; boff = kg-1024; }
    As[ak][am1] = Asrc[am1*ND + koff + ak];
    As[ak][am2] = Asrc[am2*ND + koff + ak];
    {
      const float4* s = (const float4*)(Bsrc + (size_t)(n0+bj)*bstr + boff + bkg);
      float4 b0 = s[0], b1 = s[1];
      Bs[bkg+0][bj]=b0.x; Bs[bkg+1][bj]=b0.y; Bs[bkg+2][bj]=b0.z; Bs[bkg+3][bj]=b0.w;
      Bs[bkg+4][bj]=b1.x; Bs[bkg+5][bj]=b1.y; Bs[bkg+6][bj]=b1.z; Bs[bkg+7][bj]=b1.w;
    }
    __syncthreads();
    #pragma unroll
    for (int kk=0; kk<32; ++kk){
      float a = As[kk][ty];
      float4 b = *(const float4*)&Bs[kk][tx*4];
      acc[0] += a*b.x; acc[1] += a*b.y; acc[2] += a*b.z; acc[3] += a*b.w;
    }
    __syncthreads();
  }
  *(float4*)(outp + (size_t)(ks*16+ty)*4096 + n0 + tx*4) = make_float4(acc[0],acc[1],acc[2],acc[3]);
}

__global__ __launch_bounds__(256) void gemm0_kernel(
    const float* __restrict__ attc, const float* __restrict__ z0,
    const float* __restrict__ Wih0, const float* __restrict__ Whh0, float* __restrict__ g0p){
  __shared__ float As[32][17];
  __shared__ float Bs[32][68];
  stepgemm_body(blockIdx.x, blockIdx.y, threadIdx.x, attc, z0, Wih0, 2048, 1024, Whh0, g0p, As, Bs);
}

// gemm1 (256 blocks) merged with dq for NEXT step (64 blocks)
__global__ __launch_bounds__(256) void gemm1_dq_kernel(
    const float* __restrict__ z0, const float* __restrict__ z1,
    const float* __restrict__ Wih1, const float* __restrict__ Whh1, float* __restrict__ g1p,
    const float* __restrict__ Wdec, float* __restrict__ dq){
  __shared__ float As[32][17];
  __shared__ float Bs[32][68];
  int bx = blockIdx.x;
  if (bx < 256){
    stepgemm_body(bx&63, bx>>6, threadIdx.x, z0, z1, Wih1, 1024, 0, Whh1, g1p, As, Bs);
  } else {
    dq_body(bx-256, threadIdx.x, z0, Wdec, dq);
  }
}

// ---------------- LSTM cell 0 ----------------
__global__ __launch_bounds__(256) void cell0_kernel(
    const float* __restrict__ g0p, const float* __restrict__ gey,
    float* __restrict__ z0, float* __restrict__ c0, int t){
  int idx = blockIdx.x*256 + threadIdx.x;
  int b = idx>>10, d = idx&1023;
  const float* ge = gey + ((size_t)b*NOL + t)*4096;
  float g[4];
  #pragma unroll
  for (int gi=0; gi<4; ++gi){
    float v = ge[gi*1024 + d];
    #pragma unroll
    for (int ks=0; ks<4; ++ks) v += g0p[((size_t)ks*16 + b)*4096 + gi*1024 + d];
    g[gi] = v;
  }
  float cn = sigf(g[1])*c0[idx] + sigf(g[0])*tanhf(g[2]);
  float zn = sigf(g[3])*tanhf(cn);
  c0[idx] = cn;
  z0[idx] = zn;
}

// ---------------- LSTM cell 1 (64 blocks) merged with escore for NEXT step (2048 blocks) --------
__global__ __launch_bounds__(256) void cell1_escore_kernel(
    const float* __restrict__ g1p, const float* __restrict__ bih1, const float* __restrict__ bhh1,
    float* __restrict__ z1, float* __restrict__ c1, float* __restrict__ zall, int t,
    const float* __restrict__ pre, const float* __restrict__ dq, float* __restrict__ esc){
  int bx = blockIdx.x;
  if (bx < 64){
    int idx = bx*256 + threadIdx.x;
    int b = idx>>10, d = idx&1023;
    float g[4];
    #pragma unroll
    for (int gi=0; gi<4; ++gi){
      float v = bih1[gi*1024+d] + bhh1[gi*1024+d];
      #pragma unroll
      for (int ks=0; ks<4; ++ks) v += g1p[((size_t)ks*16 + b)*4096 + gi*1024 + d];
      g[gi] = v;
    }
    float cn = sigf(g[1])*c1[idx] + sigf(g[0])*tanhf(g[2]);
    float zn = sigf(g[3])*tanhf(cn);
    c1[idx] = cn;
    z1[idx] = zn;
    zall[((size_t)b*NOL + t)*ND + d] = zn;
  } else {
    escore_body(bx-64, threadIdx.x, pre, dq, esc);
  }
}

// ---------------- per-row log_softmax + NLL + argmax ----------------
__global__ __launch_bounds__(256) void loss_kernel(
    const float* __restrict__ logits, const int* __restrict__ ys, float* __restrict__ accum){
  int row = blockIdx.x;
  int tid = threadIdx.x;
  const float* lr = logits + (size_t)row * NO;
  __shared__ float sv[256];
  __shared__ int   si[256];
  float mx = -INFINITY; int mi = 0;
  for (int n = tid; n < NO; n += 256){
    float v = lr[n];
    if (v > mx){ mx = v; mi = n; }
  }
  sv[tid] = mx; si[tid] = mi;
  __syncthreads();
  for (int s=128; s>0; s>>=1){
    if (tid < s){
      if (sv[tid+s] > sv[tid] || (sv[tid+s]==sv[tid] && si[tid+s] < si[tid])){
        sv[tid] = sv[tid+s]; si[tid] = si[tid+s];
      }
    }
    __syncthreads();
  }
  float gmx = sv[0]; int gmi = si[0];
  __syncthreads();
  float ps = 0.0f;
  for (int n = tid; n < NO; n += 256) ps += expf(lr[n]-gmx);
  sv[tid] = ps;
  __syncthreads();
  for (int s=128; s>0; s>>=1){ if (tid<s) sv[tid] += sv[tid+s]; __syncthreads(); }
  if (tid==0){
    int b = row / NOL, l = row - b*NOL;
    int label = (l < NL) ? ys[b*NL + l] : TOK_EOS;
    float lse = gmx + logf(sv[0]);
    float nll = lse - lr[label];
    atomicAdd(&accum[0], nll);
    atomicAdd(&accum[1], (gmi==label) ? 1.0f : 0.0f);
  }
}

__global__ void finalize_kernel(const float* __restrict__ accum, float* __restrict__ out){
  out[0] = accum[0] / (float)NROWS * (float)(NOL-1);
  out[1] = accum[1] / (float)NROWS;
}

extern "C" void kernel_launch(void* const* d_in, const int* in_sizes, int n_in,
                              void* d_out, int out_size, void* d_ws, size_t ws_size,
                              hipStream_t stream){
  const float* hpad  = (const float*)d_in[0];
  const int*   hlen  = (const int*)  d_in[1];
  const int*   ys    = (const int*)  d_in[2];
  const float* embed = (const float*)d_in[3];
  const float* Wenc  = (const float*)d_in[4];
  const float* Wdec  = (const float*)d_in[5];
  const float* Wih0  = (const float*)d_in[6];
  const float* Whh0  = (const float*)d_in[7];
  const float* bih0  = (const float*)d_in[8];
  const float* bhh0  = (const float*)d_in[9];
  const float* Wih1  = (const float*)d_in[10];
  const float* Whh1  = (const float*)d_in[11];
  const float* bih1  = (const float*)d_in[12];
  const float* bhh1  = (const float*)d_in[13];
  const float* Wout  = (const float*)d_in[14];
  const float* bout  = (const float*)d_in[15];
  float* out = (float*)d_out;

  float* ws = (float*)d_ws;
  size_t off = 0;
  float* pre_enc = ws + off; off += (size_t)NB*NT*NA;      // 8388608
  float* gey     = ws + off; off += (size_t)NROWS*4096;    // 8454144
  float* zall    = ws + off; off += (size_t)NROWS*ND;      // 2113536
  float* g0p     = ws + off; off += 4*16*4096;             // 262144
  float* g1p     = ws + off; off += 4*16*4096;             // 262144
  float* z0      = ws + off; off += NB*ND;                 // states contiguous:
  float* c0      = ws + off; off += NB*ND;
  float* z1      = ws + off; off += NB*ND;
  float* c1      = ws + off; off += NB*ND;
  float* accum   = ws + off; off += 8;
  float* dq      = ws + off; off += NB*NA;
  float* esc     = ws + off; off += NB*NT;
  float* attc    = ws + off; off += NB*NE;
  float* logits  = ws + off; off += (size_t)NROWS*NO;      // 20640000

  // zero z0,c0,z1,c1,accum (contiguous: 4*16384 + 8 floats)
  zero_kernel<<<257, 256, 0, stream>>>(z0, 4*NB*ND + 8);
  preenc_kernel<<<dim3(128,16), 256, 0, stream>>>(hpad, hlen, Wenc, pre_enc);
  gey_kernel<<<dim3(33,64), 256, 0, stream>>>(ys, embed, Wih0, bih0, bhh0, gey);
  // prologue: dq_0, escore_0 with z0 = 0
  dq_kernel<<<64, 256, 0, stream>>>(z0, Wdec, dq);
  escore_kernel<<<2048, 256, 0, stream>>>(pre_enc, dq, esc);

  for (int t=0; t<NOL; ++t){
    attc_kernel<<<dim3(4,16), 256, 0, stream>>>(esc, hlen, hpad, attc);
    gemm0_kernel<<<dim3(64,4), 256, 0, stream>>>(attc, z0, Wih0, Whh0, g0p);
    cell0_kernel<<<64, 256, 0, stream>>>(g0p, gey, z0, c0, t);
    // gemm1 for this step + dq for step t+1 (uses freshly-written z0)
    gemm1_dq_kernel<<<320, 256, 0, stream>>>(z0, z1, Wih1, Whh1, g1p, Wdec, dq);
    // cell1 for this step + escore for step t+1
    cell1_escore_kernel<<<2112, 256, 0, stream>>>(g1p, bih1, bhh1, z1, c1, zall, t,
                                                  pre_enc, dq, esc);
  }

  logits_kernel<<<dim3(33,157), 256, 0, stream>>>(zall, Wout, bout, logits);
  loss_kernel<<<NROWS, 256, 0, stream>>>(logits, ys, accum);
  finalize_kernel<<<1, 1, 0, stream>>>(accum, out);
}